// Round 8
// baseline (241.182 us; speedup 1.0000x reference)
//
#include <hip/hip_runtime.h>
#include <math.h>

// ManipulabilityCost: per 6x7 fp32 J: S = J*J^T, score = sqrt(det S),
// NaN->0, clamp 0.1, cost = w*(0.1-score)/0.1.
//
// NUMERICS (LOCKED — passed R4/R5/R7, absmax 1.5/1.68; arithmetic below is
// byte-identical; only data movement differs):
//   1) Gram = numpy-2.x einsum npyv/SSE3: products p0..p6, (p0+p1)+(p2+p3),
//      then +p4 +p5 +p6, no FMA.
//   2) det LU = OpenBLAS getf2_k: iamax strict->, row swap on live cols c>=j,
//      reciprocal-multiply always, ger a = fmaf(l, -u, a).
//   3) det epilogue = sign * expf(sum logf(|d_i|)), fp32.
//   4) cost epilogue fp32 throughout.
//
// PERF history: R4 159us (scalar LDS staging, serialized round-trips) ->
// R5/R7 ~68us (async DMA->LDS; R6 width=12 DMA FAILED - lane stride isn't 12).
// R5 vs R7 identical: both 14 waves/CU (LDS-limited) — block-size change
// didn't move occupancy. R8: drop LDS entirely. Each thread reads its own
// 168 contiguous bytes as 21 x float2 (8-B aligned) — 21 independent loads,
// one waitcnt, no barrier, no drain. Occupancy now VGPR-limited:
// __launch_bounds__(256,5) caps VGPR at 102 (true pressure ~95) -> 20
// waves/CU. Scattered lanes (168-B stride) are absorbed by L1 + MSHR
// same-line merging (all 21 loads outstanding back-to-back).

constexpr int MAT = 42;   // 6*7 floats per matrix
constexpr int BLK = 256;

__global__ __launch_bounds__(BLK, 5) void manip_cost_kernel(
    const float* __restrict__ jac, const float* __restrict__ wptr,
    float* __restrict__ out, int n)
{
    const long long m = (long long)blockIdx.x * BLK + threadIdx.x;
    if (m >= n) return;

    // 21 independent global_load_dwordx2 (8-B aligned: 168 = 21*8).
    float J[MAT];
    const float2* Jg = (const float2*)(jac + m * MAT);
    #pragma unroll
    for (int h = 0; h < 21; ++h) {
        float2 v = Jg[h];
        J[2 * h]     = v.x;
        J[2 * h + 1] = v.y;
    }

    // S = J J^T, numpy-2.x einsum npyv/SSE3 rounding sequence. [LOCKED]
    float A[6][6];
    #pragma unroll
    for (int i = 0; i < 6; ++i) {
        #pragma unroll
        for (int k = 0; k <= i; ++k) {
            float p[7];
            #pragma unroll
            for (int j = 0; j < 7; ++j)
                p[j] = __fmul_rn(J[i * 7 + j], J[k * 7 + j]);
            float s = __fadd_rn(__fadd_rn(p[0], p[1]), __fadd_rn(p[2], p[3]));
            s = __fadd_rn(s, p[4]);
            s = __fadd_rn(s, p[5]);
            s = __fadd_rn(s, p[6]);
            A[i][k] = s;
            A[k][i] = s;
        }
    }

    // OpenBLAS getf2_k replica (fp32). [LOCKED — swap narrowed to live cols]
    int neg = 0;
    #pragma unroll
    for (int j = 0; j < 6; ++j) {
        int p = j;
        float amax = fabsf(A[j][j]);
        #pragma unroll
        for (int r = j + 1; r < 6; ++r) {
            float v = fabsf(A[r][j]);
            if (v > amax) { amax = v; p = r; }
        }
        neg ^= (p != j);
        #pragma unroll
        for (int r = j + 1; r < 6; ++r) {
            bool sw = (p == r);
            #pragma unroll
            for (int c = j; c < 6; ++c) {   // c<j entries are dead L-storage
                float tj = A[j][c], tr = A[r][c];
                A[j][c] = sw ? tr : tj;
                A[r][c] = sw ? tj : tr;
            }
        }
        float piv = A[j][j];
        if (piv != 0.0f) {
            float rcp = 1.0f / piv;          // getf2_k: reciprocal ALWAYS
            #pragma unroll
            for (int i = j + 1; i < 6; ++i)
                A[i][j] = __fmul_rn(A[i][j], rcp);
            #pragma unroll
            for (int jj = j + 1; jj < 6; ++jj) {
                float t = -A[j][jj];
                #pragma unroll
                for (int i = j + 1; i < 6; ++i)
                    A[i][jj] = fmaf(A[i][j], t, A[i][jj]);
            }
        }
    }

    // numpy det epilogue: det = sign * expf(sum logf(|d_i|)), fp32. [LOCKED]
    float sign = neg ? -1.0f : 1.0f;
    float logdet = 0.0f;
    #pragma unroll
    for (int i = 0; i < 6; ++i) {
        float d = A[i][i];
        if (d < 0.0f) { sign = -sign; d = -d; }
        logdet = __fadd_rn(logdet, logf(d));
    }
    float det = __fmul_rn(sign, expf(logdet));

    float score = sqrtf(det);
    if (!(score == score)) score = 0.0f;
    score = fminf(score, 0.1f);
    float r = __fdiv_rn(__fsub_rn(0.1f, score), 0.1f);
    out[m] = __fmul_rn(wptr[0], r);
}

extern "C" void kernel_launch(void* const* d_in, const int* in_sizes, int n_in,
                              void* d_out, int out_size, void* d_ws, size_t ws_size,
                              hipStream_t stream) {
    const float* jac = (const float*)d_in[0];
    const float* w   = (const float*)d_in[1];
    float* out       = (float*)d_out;
    int n    = in_sizes[0] / MAT;
    int grid = (n + BLK - 1) / BLK;
    manip_cost_kernel<<<grid, BLK, 0, stream>>>(jac, w, out, n);
}